// Round 2
// baseline (1705.613 us; speedup 1.0000x reference)
//
#include <hip/hip_runtime.h>

#ifndef __has_builtin
#define __has_builtin(x) 0
#endif

typedef float v2f __attribute__((ext_vector_type(2)));

__device__ __forceinline__ float fast_exp2(float x) {
#if __has_builtin(__builtin_amdgcn_exp2f)
  return __builtin_amdgcn_exp2f(x);
#else
  return exp2f(x);
#endif
}
__device__ __forceinline__ float fast_rcp(float x) {
#if __has_builtin(__builtin_amdgcn_rcpf)
  return __builtin_amdgcn_rcpf(x);
#else
  return 1.0f / x;
#endif
}
// v_pk_fma_f32 (full-rate packed fp32 on gfx90a+) via llvm.fma.v2f32
__device__ __forceinline__ v2f pk_fma(v2f a, v2f b, v2f c) {
  return __builtin_elementwise_fma(a, b, c);
}

namespace {
constexpr int kB = 131072;
constexpr int kSeq = 150;
constexpr int kD = 2;
constexpr int kH = 64;
constexpr int kPred = 150;
constexpr int kSteps = kPred - 1;          // 149
constexpr float kDt = 150.0f / 149.0f;     // linspace(0,150,150) spacing
constexpr float kC = 2.8853900817779268f;  // 2*log2(e)
// |q| > 8.4  <=>  |p| = C*|q| > 24.24 ; clamp err 2e^-16.8 ~ 1e-7 (< fp32 eps)
constexpr float kSatP = 24.25f;
}  // namespace

// f(y) = tanh(y@W1+b1)@W2 + b2, folded:
//   tanh(q) = 1 - 2*r,  r = rcp(1 + exp2(C*q))
//   p_j = C*(W1[0][j]*y0 + W1[1][j]*y1 + b1[j])
//   acc_d = base_d + sum_j r_j * (-2*W2[j][d]),  base_d = b2[d] + sum_j W2[j][d]
__device__ __forceinline__ void feval(
    float y0, float y1, const float4* __restrict__ swx,
    const float4* __restrict__ swy, const float4* __restrict__ sbb,
    const float4* __restrict__ swz, const float4* __restrict__ sww,
    float base0, float base1, float& f0, float& f1) {
  const v2f y0v = {y0, y0}, y1v = {y1, y1};
  v2f a0 = {0.f, 0.f}, a1 = {0.f, 0.f};  // units 4g+0,4g+1
  v2f c0 = {0.f, 0.f}, c1 = {0.f, 0.f};  // units 4g+2,4g+3
#pragma unroll 4
  for (int g = 0; g < kH / 4; ++g) {
    const float4 wx = swx[g], wy = swy[g], bb = sbb[g];
    const float4 wz = swz[g], ww = sww[g];
    v2f p01 = pk_fma(y0v, (v2f){wx.x, wx.y},
                     pk_fma(y1v, (v2f){wy.x, wy.y}, (v2f){bb.x, bb.y}));
    v2f p23 = pk_fma(y0v, (v2f){wx.z, wx.w},
                     pk_fma(y1v, (v2f){wy.z, wy.w}, (v2f){bb.z, bb.w}));
    // wave-uniform saturation test: min over the 4 units of |p|
    float m = fminf(fminf(fabsf(p01.x), fabsf(p01.y)),
                    fminf(fabsf(p23.x), fabsf(p23.y)));
    v2f r01, r23;
    if (__all(m > kSatP)) {
      // all 64 lanes, all 4 units saturated: tanh = sign(p) => r = (p<0)
      r01.x = p01.x < 0.f ? 1.f : 0.f;
      r01.y = p01.y < 0.f ? 1.f : 0.f;
      r23.x = p23.x < 0.f ? 1.f : 0.f;
      r23.y = p23.y < 0.f ? 1.f : 0.f;
    } else {
      v2f t01 = {fast_exp2(p01.x), fast_exp2(p01.y)};
      v2f t23 = {fast_exp2(p23.x), fast_exp2(p23.y)};
      t01 = t01 + (v2f){1.f, 1.f};  // v_pk_add_f32
      t23 = t23 + (v2f){1.f, 1.f};
      r01.x = fast_rcp(t01.x);
      r01.y = fast_rcp(t01.y);
      r23.x = fast_rcp(t23.x);
      r23.y = fast_rcp(t23.y);
    }
    a0 = pk_fma(r01, (v2f){wz.x, wz.y}, a0);
    c0 = pk_fma(r23, (v2f){wz.z, wz.w}, c0);
    a1 = pk_fma(r01, (v2f){ww.x, ww.y}, a1);
    c1 = pk_fma(r23, (v2f){ww.z, ww.w}, c1);
  }
  f0 = base0 + ((a0.x + a0.y) + (c0.x + c0.y));
  f1 = base1 + ((a1.x + a1.y) + (c1.x + c1.y));
}

__global__ __launch_bounds__(256, 2) void ode_kernel(
    const float* __restrict__ x, const float* __restrict__ W1,
    const float* __restrict__ b1, const float* __restrict__ W2,
    const float* __restrict__ b2, float* __restrict__ out) {
  // SoA weight layout, one float4 = 4 hidden units per array
  __shared__ float4 swx[kH / 4], swy[kH / 4], sbb[kH / 4];
  __shared__ float4 swz[kH / 4], sww[kH / 4];
  __shared__ float sbase[2];

  const int t = threadIdx.x;
  if (t < kH) {
    // W1 (D,H) row-major; W2 (H,D) row-major
    reinterpret_cast<float*>(swx)[t] = W1[t] * kC;
    reinterpret_cast<float*>(swy)[t] = W1[kH + t] * kC;
    reinterpret_cast<float*>(sbb)[t] = b1[t] * kC;
    reinterpret_cast<float*>(swz)[t] = -2.0f * W2[2 * t];
    reinterpret_cast<float*>(sww)[t] = -2.0f * W2[2 * t + 1];
  }
  if (t < 2) {
    float s = b2[t];
    for (int j = 0; j < kH; ++j) s += W2[2 * j + t];
    sbase[t] = s;
  }
  __syncthreads();
  const float base0 = sbase[0], base1 = sbase[1];

  const long bidx = (long)blockIdx.x * blockDim.x + t;
  const float* xp = x + bidx * (long)(kSeq * kD) + (kSeq - 1) * kD;
  float y0 = xp[0];
  float y1 = xp[1];
  float* op = out + bidx * (long)(kPred * kD);

  float py0 = y0, py1 = y1;  // previous even-index state for paired stores
  constexpr float DT = kDt, DT3 = kDt / 3.0f, DT8 = kDt / 8.0f;

  for (int s = 1; s <= kSteps; ++s) {
    float k1x, k1y, k2x, k2y, k3x, k3y, k4x, k4y;
    feval(y0, y1, swx, swy, sbb, swz, sww, base0, base1, k1x, k1y);
    feval(fmaf(DT3, k1x, y0), fmaf(DT3, k1y, y1), swx, swy, sbb, swz, sww,
          base0, base1, k2x, k2y);
    feval(fmaf(DT, k2x, fmaf(-DT3, k1x, y0)),
          fmaf(DT, k2y, fmaf(-DT3, k1y, y1)), swx, swy, sbb, swz, sww, base0,
          base1, k3x, k3y);
    feval(fmaf(DT, k1x - k2x + k3x, y0), fmaf(DT, k1y - k2y + k3y, y1), swx,
          swy, sbb, swz, sww, base0, base1, k4x, k4y);
    y0 = fmaf(DT8, k1x + 3.0f * (k2x + k3x) + k4x, y0);
    y1 = fmaf(DT8, k1y + 3.0f * (k2y + k3y) + k4y, y1);

    if (s & 1) {
      float4 v = make_float4(py0, py1, y0, y1);
      *reinterpret_cast<float4*>(op + (long)(s - 1) * 2) = v;
    } else {
      py0 = y0;
      py1 = y1;
    }
  }
}

extern "C" void kernel_launch(void* const* d_in, const int* in_sizes, int n_in,
                              void* d_out, int out_size, void* d_ws,
                              size_t ws_size, hipStream_t stream) {
  const float* x = (const float*)d_in[0];
  const float* W1 = (const float*)d_in[1];
  const float* b1 = (const float*)d_in[2];
  const float* W2 = (const float*)d_in[3];
  const float* b2 = (const float*)d_in[4];
  float* out = (float*)d_out;

  dim3 grid(kB / 256);
  dim3 block(256);
  hipLaunchKernelGGL(ode_kernel, grid, block, 0, stream, x, W1, b1, W2, b2,
                     out);
}